// Round 1
// baseline (16165.230 us; speedup 1.0000x reference)
//
#include <hip/hip_runtime.h>
#include <stdint.h>

#define B 64
#define S 512
#define E 512
#define H 1024
#define NCLS 4

typedef __attribute__((ext_vector_type(8))) short short8;
typedef __attribute__((ext_vector_type(4))) float f32x4;

__device__ __forceinline__ unsigned short f32_to_bf16(float f) {
    unsigned int x = __float_as_uint(f);
    unsigned int r = (x + 0x7fffu + ((x >> 16) & 1u)) >> 16;   // RNE
    return (unsigned short)r;
}
__device__ __forceinline__ float bf16_to_f32(unsigned short u) {
    return __uint_as_float(((unsigned int)u) << 16);
}

// ---------------------------------------------------------------------------
// K1: wx[s][b][j] = sum_k emb[x[b*S+s]][k] * W[j][k] + b_w[j], stored bf16.
// 128x128 tile, BK=32, 4 waves (2x2), 16x16x32 bf16 MFMA, single-buffer LDS.
// ---------------------------------------------------------------------------
#define K1_LDA 40   // bf16 elems per row slot (32 + 8 pad) = 80B, 16B-aligned

__global__ __launch_bounds__(256) void k_wx_gemm(
    const int* __restrict__ x, const float* __restrict__ emb,
    const float* __restrict__ W, const float* __restrict__ bw,
    unsigned short* __restrict__ wx)
{
    __shared__ unsigned short Asub[128 * K1_LDA];
    __shared__ unsigned short Bsub[128 * K1_LDA];

    const int t  = threadIdx.x;
    const int mt = blockIdx.x;            // 0..255  (M tiles, M = 32768)
    const int nt = blockIdx.y;            // 0..7    (N tiles, N = 1024)
    const int i0 = mt * 128;
    const int j0 = nt * 128;

    // staging role: thread covers 16 k-elems of one row
    const int r  = t >> 1;                // 0..127
    const int kh = (t & 1) * 16;          // 0 or 16
    const int tok = x[i0 + r];
    const float* arow = emb + (size_t)tok * E;
    const float* brow = W + (size_t)(j0 + r) * E;

    // mfma role
    const int lane = t & 63;
    const int w    = t >> 6;
    const int wm   = (w >> 1) * 64;
    const int wn   = (w & 1) * 64;
    const int fr   = lane & 15;
    const int kg   = lane >> 4;           // 0..3

    f32x4 acc[4][4] = {};

    for (int kt = 0; kt < E; kt += 32) {
        __syncthreads();
        {
            union { unsigned short us[8]; uint4 v; } p;
            const float* srcA = arow + kt + kh;
            #pragma unroll
            for (int i = 0; i < 8; ++i) p.us[i] = f32_to_bf16(srcA[i]);
            *(uint4*)&Asub[r * K1_LDA + kh] = p.v;
            #pragma unroll
            for (int i = 0; i < 8; ++i) p.us[i] = f32_to_bf16(srcA[8 + i]);
            *(uint4*)&Asub[r * K1_LDA + kh + 8] = p.v;
            const float* srcB = brow + kt + kh;
            #pragma unroll
            for (int i = 0; i < 8; ++i) p.us[i] = f32_to_bf16(srcB[i]);
            *(uint4*)&Bsub[r * K1_LDA + kh] = p.v;
            #pragma unroll
            for (int i = 0; i < 8; ++i) p.us[i] = f32_to_bf16(srcB[8 + i]);
            *(uint4*)&Bsub[r * K1_LDA + kh + 8] = p.v;
        }
        __syncthreads();

        short8 a[4], b[4];
        #pragma unroll
        for (int mi = 0; mi < 4; ++mi)
            a[mi] = *(const short8*)&Asub[(wm + mi * 16 + fr) * K1_LDA + kg * 8];
        #pragma unroll
        for (int ni = 0; ni < 4; ++ni)
            b[ni] = *(const short8*)&Bsub[(wn + ni * 16 + fr) * K1_LDA + kg * 8];
        #pragma unroll
        for (int mi = 0; mi < 4; ++mi)
            #pragma unroll
            for (int ni = 0; ni < 4; ++ni)
                acc[mi][ni] = __builtin_amdgcn_mfma_f32_16x16x32_bf16(
                                  a[mi], b[ni], acc[mi][ni], 0, 0, 0);
    }

    // epilogue: D element (m = kg*4+rr, n = lane&15) per 16x16 tile
    float bwv[4];
    #pragma unroll
    for (int ni = 0; ni < 4; ++ni) bwv[ni] = bw[j0 + wn + ni * 16 + fr];
    #pragma unroll
    for (int mi = 0; mi < 4; ++mi) {
        #pragma unroll
        for (int ni = 0; ni < 4; ++ni) {
            const int gn = j0 + wn + ni * 16 + fr;
            #pragma unroll
            for (int rr = 0; rr < 4; ++rr) {
                const int gm = i0 + wm + mi * 16 + kg * 4 + rr;
                const int bb = gm >> 9;         // i = b*512 + s
                const int ss = gm & 511;
                wx[(size_t)(ss * B + bb) * H + gn] =
                    f32_to_bf16(acc[mi][ni][rr] + bwv[ni]);
            }
        }
    }
}

// ---------------------------------------------------------------------------
// K2: persistent recurrence. 256 wgs x 256 thr (1 wg/CU via 140KB LDS).
// group g = blockIdx%8 owns batches [8g,8g+8); member m = blockIdx/8 owns
// U rows [32m,32m+32) resident in LDS (f32). Per step: partial matvec
// (thread = 1 j x 8 batches x 128 k), LDS reduce over 8 k-slices, tanh,
// publish h (global double buffer), 32-member atomic barrier + fences.
// ---------------------------------------------------------------------------
#define U_STRIDE 1028          // 1024 + 4 pad (16B-aligned rows)
#define REDJ 9                 // 8 batches + 1 pad (bank spread)

__global__ __launch_bounds__(256) void k_rnn(
    const unsigned short* __restrict__ wx, const float* __restrict__ U,
    const float* __restrict__ V, const float* __restrict__ bv,
    float* __restrict__ hbuf, unsigned int* __restrict__ ctr,
    float* __restrict__ out)
{
    __shared__ float U_lds[32 * U_STRIDE];     // 131584 B
    __shared__ float red[8 * 32 * REDJ];       //   9216 B

    const int t   = threadIdx.x;
    const int g   = blockIdx.x & 7;
    const int m   = blockIdx.x >> 3;
    const int j0  = m * 32;
    const int bg0 = g * 8;

    // stage this wg's 32 U rows into LDS (f32, coalesced)
    for (int rr = 0; rr < 32; ++rr) {
        *(f32x4*)&U_lds[rr * U_STRIDE + t * 4] =
            *(const f32x4*)(U + (size_t)(j0 + rr) * H + t * 4);
    }
    __syncthreads();

    const int j_c = t & 31, ks = t >> 5, k0 = ks * 128;   // compute mapping
    const int b_o = t >> 5, j_o = t & 31;                 // output mapping
    unsigned int* gc = ctr + g;

    for (int ts = 0; ts < S; ++ts) {
        const int rb = ts & 1;
        const float* hr = hbuf + rb * (B * H);
        float*       hw = hbuf + (rb ^ 1) * (B * H);

        const float wxv = bf16_to_f32(
            wx[(size_t)(ts * B + bg0 + b_o) * H + j0 + j_o]);

        float acc[8] = {};
        const float* ub = &U_lds[j_c * U_STRIDE + k0];
        const float* hb = hr + (size_t)bg0 * H + k0;
        #pragma unroll 2
        for (int kk = 0; kk < 128; kk += 4) {
            const f32x4 u4 = *(const f32x4*)&ub[kk];
            #pragma unroll
            for (int bi = 0; bi < 8; ++bi) {
                const f32x4 h4 = *(const f32x4*)&hb[bi * H + kk];
                acc[bi] += u4[0]*h4[0] + u4[1]*h4[1] + u4[2]*h4[2] + u4[3]*h4[3];
            }
        }

        #pragma unroll
        for (int bi = 0; bi < 8; ++bi)
            red[ks * (32 * REDJ) + j_c * REDJ + bi] = acc[bi];
        __syncthreads();

        float sum = 0.f;
        #pragma unroll
        for (int p = 0; p < 8; ++p)
            sum += red[p * (32 * REDJ) + j_o * REDJ + b_o];

        const float hv = tanhf(wxv + sum);
        hw[(size_t)(bg0 + b_o) * H + j0 + j_o] = hv;

        // ---- group barrier: 32 members, device-scope ----
        __syncthreads();                       // wg stores done (vmcnt drained)
        if (t == 0) {
            __threadfence();                   // release to device scope
            __hip_atomic_fetch_add(gc, 1u, __ATOMIC_ACQ_REL,
                                   __HIP_MEMORY_SCOPE_AGENT);
            const unsigned int tgt = 32u * (unsigned)(ts + 1);
            while (__hip_atomic_load(gc, __ATOMIC_RELAXED,
                                     __HIP_MEMORY_SCOPE_AGENT) < tgt) {}
        }
        __syncthreads();
        __threadfence();                       // acquire: invalidate stale caches
    }

    // final projection: out[b][c] = h_final[b] . V[c] + bv[c]  (member 0 only)
    if (m == 0) {
        const float* hf = hbuf + ((S & 1) ? (B * H) : 0);
        const int o = t & 31, part = t >> 5;
        const int bi = o >> 2, c = o & 3;
        const float* hrow = hf + (size_t)(bg0 + bi) * H;
        const float* vrow = V + (size_t)c * H;
        float partial = 0.f;
        for (int jj = part * 128; jj < part * 128 + 128; ++jj)
            partial += vrow[jj] * hrow[jj];
        red[part * 32 + o] = partial;
        __syncthreads();
        if (t < 32) {
            float sv = 0.f;
            #pragma unroll
            for (int p = 0; p < 8; ++p) sv += red[p * 32 + t];
            out[(bg0 + (t >> 2)) * NCLS + (t & 3)] = sv + bv[t & 3];
        }
    }
}

// ---------------------------------------------------------------------------
extern "C" void kernel_launch(void* const* d_in, const int* in_sizes, int n_in,
                              void* d_out, int out_size, void* d_ws, size_t ws_size,
                              hipStream_t stream)
{
    const int*   x   = (const int*)d_in[0];
    const float* emb = (const float*)d_in[1];
    const float* W   = (const float*)d_in[2];
    const float* bw  = (const float*)d_in[3];
    const float* U   = (const float*)d_in[4];
    const float* V   = (const float*)d_in[5];
    const float* bv  = (const float*)d_in[6];
    float* out = (float*)d_out;

    unsigned short* wx = (unsigned short*)d_ws;
    const size_t WX_BYTES = (size_t)S * B * H * sizeof(unsigned short); // 64 MiB
    float* hbuf = (float*)((char*)d_ws + WX_BYTES);
    const size_t HB_BYTES = (size_t)2 * B * H * sizeof(float);          // 512 KiB
    unsigned int* ctr = (unsigned int*)((char*)d_ws + WX_BYTES + HB_BYTES);

    // zero h0 double-buffer + barrier counters every call (ws not re-poisoned)
    hipMemsetAsync((char*)d_ws + WX_BYTES, 0, HB_BYTES + 64, stream);

    hipLaunchKernelGGL(k_wx_gemm, dim3(256, 8), dim3(256), 0, stream,
                       x, emb, W, bw, wx);
    hipLaunchKernelGGL(k_rnn, dim3(256), dim3(256), 0, stream,
                       wx, U, V, bv, hbuf, ctr, out);
}

// Round 2
// 15902.281 us; speedup vs baseline: 1.0165x; 1.0165x over previous
//
#include <hip/hip_runtime.h>
#include <stdint.h>

#define B 64
#define S 512
#define E 512
#define H 1024
#define NCLS 4

typedef __attribute__((ext_vector_type(8))) short short8;
typedef __attribute__((ext_vector_type(4))) float f32x4;

__device__ __forceinline__ unsigned short f32_to_bf16(float f) {
    unsigned int x = __float_as_uint(f);
    unsigned int r = (x + 0x7fffu + ((x >> 16) & 1u)) >> 16;   // RNE
    return (unsigned short)r;
}
__device__ __forceinline__ float bf16_to_f32(unsigned short u) {
    return __uint_as_float(((unsigned int)u) << 16);
}

// ---------------------------------------------------------------------------
// K1: wx[s][b][j] = sum_k emb[x[b*S+s]][k] * W[j][k] + b_w[j], stored bf16.
// 128x128 tile, BK=32, 4 waves (2x2), 16x16x32 bf16 MFMA. (unchanged; fast)
// ---------------------------------------------------------------------------
#define K1_LDA 40

__global__ __launch_bounds__(256) void k_wx_gemm(
    const int* __restrict__ x, const float* __restrict__ emb,
    const float* __restrict__ W, const float* __restrict__ bw,
    unsigned short* __restrict__ wx)
{
    __shared__ unsigned short Asub[128 * K1_LDA];
    __shared__ unsigned short Bsub[128 * K1_LDA];

    const int t  = threadIdx.x;
    const int mt = blockIdx.x;
    const int nt = blockIdx.y;
    const int i0 = mt * 128;
    const int j0 = nt * 128;

    const int r  = t >> 1;
    const int kh = (t & 1) * 16;
    const int tok = x[i0 + r];
    const float* arow = emb + (size_t)tok * E;
    const float* brow = W + (size_t)(j0 + r) * E;

    const int lane = t & 63;
    const int w    = t >> 6;
    const int wm   = (w >> 1) * 64;
    const int wn   = (w & 1) * 64;
    const int fr   = lane & 15;
    const int kg   = lane >> 4;

    f32x4 acc[4][4] = {};

    for (int kt = 0; kt < E; kt += 32) {
        __syncthreads();
        {
            union { unsigned short us[8]; uint4 v; } p;
            const float* srcA = arow + kt + kh;
            #pragma unroll
            for (int i = 0; i < 8; ++i) p.us[i] = f32_to_bf16(srcA[i]);
            *(uint4*)&Asub[r * K1_LDA + kh] = p.v;
            #pragma unroll
            for (int i = 0; i < 8; ++i) p.us[i] = f32_to_bf16(srcA[8 + i]);
            *(uint4*)&Asub[r * K1_LDA + kh + 8] = p.v;
            const float* srcB = brow + kt + kh;
            #pragma unroll
            for (int i = 0; i < 8; ++i) p.us[i] = f32_to_bf16(srcB[i]);
            *(uint4*)&Bsub[r * K1_LDA + kh] = p.v;
            #pragma unroll
            for (int i = 0; i < 8; ++i) p.us[i] = f32_to_bf16(srcB[8 + i]);
            *(uint4*)&Bsub[r * K1_LDA + kh + 8] = p.v;
        }
        __syncthreads();

        short8 a[4], b[4];
        #pragma unroll
        for (int mi = 0; mi < 4; ++mi)
            a[mi] = *(const short8*)&Asub[(wm + mi * 16 + fr) * K1_LDA + kg * 8];
        #pragma unroll
        for (int ni = 0; ni < 4; ++ni)
            b[ni] = *(const short8*)&Bsub[(wn + ni * 16 + fr) * K1_LDA + kg * 8];
        #pragma unroll
        for (int mi = 0; mi < 4; ++mi)
            #pragma unroll
            for (int ni = 0; ni < 4; ++ni)
                acc[mi][ni] = __builtin_amdgcn_mfma_f32_16x16x32_bf16(
                                  a[mi], b[ni], acc[mi][ni], 0, 0, 0);
    }

    float bwv[4];
    #pragma unroll
    for (int ni = 0; ni < 4; ++ni) bwv[ni] = bw[j0 + wn + ni * 16 + fr];
    #pragma unroll
    for (int mi = 0; mi < 4; ++mi) {
        #pragma unroll
        for (int ni = 0; ni < 4; ++ni) {
            const int gn = j0 + wn + ni * 16 + fr;
            #pragma unroll
            for (int rr = 0; rr < 4; ++rr) {
                const int gm = i0 + wm + mi * 16 + kg * 4 + rr;
                const int bb = gm >> 9;
                const int ss = gm & 511;
                wx[(size_t)(ss * B + bb) * H + gn] =
                    f32_to_bf16(acc[mi][ni][rr] + bwv[ni]);
            }
        }
    }
}

// ---------------------------------------------------------------------------
// K2: persistent recurrence, latency-optimized.
//  - 8 groups x 32 members (1 wg/CU). Member m: U rows [32m,32m+32) in LDS.
//  - Per step: distributed flag wait -> bulk-stage group h (32KB) into LDS
//    (XOR-swizzled) -> compute (thread = 2j x 8b x 64k) -> shfl_xor reduce
//    over 16 k-slices -> tanh -> publish + per-member release flag.
//  - LDS: U 32x1024 f32 + h 8x1024 f32 = 163840 B (exact max).
// ---------------------------------------------------------------------------
__global__ __launch_bounds__(256) void k_rnn(
    const unsigned short* __restrict__ wx, const float* __restrict__ U,
    const float* __restrict__ Vw, const float* __restrict__ bv,
    float* __restrict__ hbuf, unsigned int* __restrict__ flags,
    float* __restrict__ out)
{
    __shared__ float U_lds[32 * 1024];   // 131072 B (swizzled)
    __shared__ float h_lds[8 * 1024];    //  32768 B (swizzled)

    const int t   = threadIdx.x;
    const int g   = blockIdx.x & 7;      // group: batches [8g, 8g+8)
    const int m   = blockIdx.x >> 3;     // member: j rows [32m, 32m+32)
    const int j0  = m * 32;
    const int bg0 = g * 8;

    // ---- stage U rows into LDS (swizzled: word k -> k ^ (((k>>6)&7)<<2)) ----
    {
        const int ksb = (t >> 4) & 7;
        const int dst = 4 * (t ^ ksb);          // == (t*4) ^ (ksb<<2)
        for (int rr = 0; rr < 32; ++rr) {
            f32x4 v = *(const f32x4*)(U + (size_t)(j0 + rr) * H + t * 4);
            *(f32x4*)&U_lds[rr * 1024 + dst] = v;
        }
    }

    // compute-role mapping
    const int ks = t & 15;               // k-slice (64 k each)
    const int j2 = t >> 4;               // j-unit (2 rows each)
    const int k0 = ks * 64;
    const int sw = (ks & 7) << 2;        // swizzle for this slice

    // staging-role mapping: thread stages h[sb][smem*32 .. +32)
    const int sb   = t >> 5;
    const int smem = t & 31;
    const int sksb = (smem >> 1) & 7;

    // output element owned by this thread after allreduce
    const int jj = ks & 1, bi = ks >> 1;
    const int out_j = j0 + j2 * 2 + jj;
    const int out_b = bg0 + bi;

    unsigned int* fl = flags + g * 32;
    unsigned int* myflag = fl + m;

    float wxv = bf16_to_f32(wx[(size_t)(0 * B + out_b) * H + out_j]);

    __syncthreads();                     // U resident

    for (int ts = 0; ts < S; ++ts) {
        const float* hr = hbuf + (ts & 1) * (B * H);
        float*       hw = hbuf + ((ts + 1) & 1) * (B * H);

        // wait for the member whose chunk we stage (flag = steps published)
        while (__hip_atomic_load(&fl[smem], __ATOMIC_RELAXED,
                                 __HIP_MEMORY_SCOPE_AGENT) < (unsigned)ts) {}
        __threadfence();                 // acquire: invalidate stale caches

        // prefetch next step's wx (h-independent)
        float wx_next = 0.f;
        if (ts + 1 < S)
            wx_next = bf16_to_f32(wx[(size_t)((ts + 1) * B + out_b) * H + out_j]);

        // bulk-stage 128B of h into LDS (swizzled)
        {
            const float* src = hr + (size_t)(bg0 + sb) * H + smem * 32;
            float* dstb = &h_lds[sb * 1024 + smem * 32];
            #pragma unroll
            for (int c = 0; c < 8; ++c) {
                f32x4 v = *(const f32x4*)(src + c * 4);
                *(f32x4*)&dstb[4 * (c ^ sksb)] = v;
            }
        }
        __syncthreads();

        // compute: acc[jj 2][b 8] over k-slice [k0, k0+64)
        float acc[2][8] = {};
        const float* ub0 = &U_lds[(j2 * 2    ) * 1024 + k0];
        const float* ub1 = &U_lds[(j2 * 2 + 1) * 1024 + k0];
        const float* hb  = &h_lds[k0];
        #pragma unroll 4
        for (int kk = 0; kk < 64; kk += 4) {
            const int ko = kk ^ sw;
            const f32x4 u0 = *(const f32x4*)&ub0[ko];
            const f32x4 u1 = *(const f32x4*)&ub1[ko];
            #pragma unroll
            for (int bq = 0; bq < 8; ++bq) {
                const f32x4 h4 = *(const f32x4*)&hb[bq * 1024 + ko];
                acc[0][bq] += u0[0]*h4[0] + u0[1]*h4[1] + u0[2]*h4[2] + u0[3]*h4[3];
                acc[1][bq] += u1[0]*h4[0] + u1[1]*h4[1] + u1[2]*h4[2] + u1[3]*h4[3];
            }
        }

        // butterfly allreduce over the 16 k-slices (lanes t&15)
        #pragma unroll
        for (int q = 0; q < 16; ++q) {
            float v = acc[q & 1][q >> 1];
            v += __shfl_xor(v, 1);
            v += __shfl_xor(v, 2);
            v += __shfl_xor(v, 4);
            v += __shfl_xor(v, 8);
            acc[q & 1][q >> 1] = v;
        }
        // lane ks takes output q = ks (compile-time indexed select chain)
        float sum = 0.f;
        #pragma unroll
        for (int q = 0; q < 16; ++q)
            if (ks == q) sum = acc[q & 1][q >> 1];

        float p = wxv + sum;
        p = fminf(fmaxf(p, -15.f), 15.f);
        const float e  = __expf(2.0f * p);
        const float hv = 1.0f - 2.0f / (e + 1.0f);
        hw[(size_t)out_b * H + out_j] = hv;

        __syncthreads();                 // wg stores drained (vmcnt 0 at barrier)
        if (t == 0) {
            __threadfence();             // release: write back L2
            __hip_atomic_store(myflag, (unsigned)(ts + 1), __ATOMIC_RELEASE,
                               __HIP_MEMORY_SCOPE_AGENT);
        }
        wxv = wx_next;
    }

    // ---- final projection: out[b][c] = h_final[b] . V[c] + bv[c] ----
    if (m == 0) {
        while (__hip_atomic_load(&fl[t & 31], __ATOMIC_RELAXED,
                                 __HIP_MEMORY_SCOPE_AGENT) < (unsigned)S) {}
        __threadfence();
        const float* hf = hbuf;          // buf[(511+1)&1] = buf0
        const int o = t & 31, part = t >> 5;
        const int pb = o >> 2, c = o & 3;
        const float* hrow = hf + (size_t)(bg0 + pb) * H;
        const float* vrow = Vw + (size_t)c * H;
        float partial = 0.f;
        for (int jq = part * 128; jq < part * 128 + 128; ++jq)
            partial += vrow[jq] * hrow[jq];
        __syncthreads();
        h_lds[part * 32 + o] = partial;
        __syncthreads();
        if (t < 32) {
            float sv = 0.f;
            #pragma unroll
            for (int pq = 0; pq < 8; ++pq) sv += h_lds[pq * 32 + t];
            out[(bg0 + (t >> 2)) * NCLS + (t & 3)] = sv + bv[t & 3];
        }
    }
}

// ---------------------------------------------------------------------------
extern "C" void kernel_launch(void* const* d_in, const int* in_sizes, int n_in,
                              void* d_out, int out_size, void* d_ws, size_t ws_size,
                              hipStream_t stream)
{
    const int*   x   = (const int*)d_in[0];
    const float* emb = (const float*)d_in[1];
    const float* W   = (const float*)d_in[2];
    const float* bw  = (const float*)d_in[3];
    const float* U   = (const float*)d_in[4];
    const float* V   = (const float*)d_in[5];
    const float* bv  = (const float*)d_in[6];
    float* out = (float*)d_out;

    unsigned short* wx = (unsigned short*)d_ws;
    const size_t WX_BYTES = (size_t)S * B * H * sizeof(unsigned short); // 64 MiB
    float* hbuf = (float*)((char*)d_ws + WX_BYTES);
    const size_t HB_BYTES = (size_t)2 * B * H * sizeof(float);          // 512 KiB
    unsigned int* flags = (unsigned int*)((char*)d_ws + WX_BYTES + HB_BYTES);

    // zero h0 double-buffer + flags every call (ws is not re-poisoned)
    hipMemsetAsync((char*)d_ws + WX_BYTES, 0, HB_BYTES + 1024, stream);

    hipLaunchKernelGGL(k_wx_gemm, dim3(256, 8), dim3(256), 0, stream,
                       x, emb, W, bw, wx);
    hipLaunchKernelGGL(k_rnn, dim3(256), dim3(256), 0, stream,
                       wx, U, V, bv, hbuf, flags, out);
}

// Round 3
// 5042.858 us; speedup vs baseline: 3.2056x; 3.1534x over previous
//
#include <hip/hip_runtime.h>
#include <stdint.h>

#define B 64
#define S 512
#define E 512
#define H 1024
#define NCLS 4

typedef __attribute__((ext_vector_type(8))) short short8;
typedef __attribute__((ext_vector_type(4))) float f32x4;

__device__ __forceinline__ unsigned short f32_to_bf16(float f) {
    unsigned int x = __float_as_uint(f);
    unsigned int r = (x + 0x7fffu + ((x >> 16) & 1u)) >> 16;   // RNE
    return (unsigned short)r;
}
__device__ __forceinline__ float bf16_to_f32(unsigned short u) {
    return __uint_as_float(((unsigned int)u) << 16);
}

// Cache-bypassing (MALL-coherent) accesses: sc0 sc1 = bypass L1 + L2.
__device__ __forceinline__ f32x4 load_sc16(const float* p) {
    f32x4 v;
    asm volatile("global_load_dwordx4 %0, %1, off sc0 sc1"
                 : "=v"(v) : "v"(p) : "memory");
    return v;
}
__device__ __forceinline__ void store_sc4(float* p, float v) {
    asm volatile("global_store_dword %0, %1, off sc0 sc1"
                 :: "v"(p), "v"(v) : "memory");
}

// ---------------------------------------------------------------------------
// K1: wx[s][b][j] = sum_k emb[x[b*S+s]][k] * W[j][k] + b_w[j], stored bf16.
// 128x128 tile, BK=32, 4 waves (2x2), 16x16x32 bf16 MFMA. (unchanged)
// ---------------------------------------------------------------------------
#define K1_LDA 40

__global__ __launch_bounds__(256) void k_wx_gemm(
    const int* __restrict__ x, const float* __restrict__ emb,
    const float* __restrict__ W, const float* __restrict__ bw,
    unsigned short* __restrict__ wx)
{
    __shared__ unsigned short Asub[128 * K1_LDA];
    __shared__ unsigned short Bsub[128 * K1_LDA];

    const int t  = threadIdx.x;
    const int mt = blockIdx.x;
    const int nt = blockIdx.y;
    const int i0 = mt * 128;
    const int j0 = nt * 128;

    const int r  = t >> 1;
    const int kh = (t & 1) * 16;
    const int tok = x[i0 + r];
    const float* arow = emb + (size_t)tok * E;
    const float* brow = W + (size_t)(j0 + r) * E;

    const int lane = t & 63;
    const int w    = t >> 6;
    const int wm   = (w >> 1) * 64;
    const int wn   = (w & 1) * 64;
    const int fr   = lane & 15;
    const int kg   = lane >> 4;

    f32x4 acc[4][4] = {};

    for (int kt = 0; kt < E; kt += 32) {
        __syncthreads();
        {
            union { unsigned short us[8]; uint4 v; } p;
            const float* srcA = arow + kt + kh;
            #pragma unroll
            for (int i = 0; i < 8; ++i) p.us[i] = f32_to_bf16(srcA[i]);
            *(uint4*)&Asub[r * K1_LDA + kh] = p.v;
            #pragma unroll
            for (int i = 0; i < 8; ++i) p.us[i] = f32_to_bf16(srcA[8 + i]);
            *(uint4*)&Asub[r * K1_LDA + kh + 8] = p.v;
            const float* srcB = brow + kt + kh;
            #pragma unroll
            for (int i = 0; i < 8; ++i) p.us[i] = f32_to_bf16(srcB[i]);
            *(uint4*)&Bsub[r * K1_LDA + kh] = p.v;
            #pragma unroll
            for (int i = 0; i < 8; ++i) p.us[i] = f32_to_bf16(srcB[8 + i]);
            *(uint4*)&Bsub[r * K1_LDA + kh + 8] = p.v;
        }
        __syncthreads();

        short8 a[4], b[4];
        #pragma unroll
        for (int mi = 0; mi < 4; ++mi)
            a[mi] = *(const short8*)&Asub[(wm + mi * 16 + fr) * K1_LDA + kg * 8];
        #pragma unroll
        for (int ni = 0; ni < 4; ++ni)
            b[ni] = *(const short8*)&Bsub[(wn + ni * 16 + fr) * K1_LDA + kg * 8];
        #pragma unroll
        for (int mi = 0; mi < 4; ++mi)
            #pragma unroll
            for (int ni = 0; ni < 4; ++ni)
                acc[mi][ni] = __builtin_amdgcn_mfma_f32_16x16x32_bf16(
                                  a[mi], b[ni], acc[mi][ni], 0, 0, 0);
    }

    float bwv[4];
    #pragma unroll
    for (int ni = 0; ni < 4; ++ni) bwv[ni] = bw[j0 + wn + ni * 16 + fr];
    #pragma unroll
    for (int mi = 0; mi < 4; ++mi) {
        #pragma unroll
        for (int ni = 0; ni < 4; ++ni) {
            const int gn = j0 + wn + ni * 16 + fr;
            #pragma unroll
            for (int rr = 0; rr < 4; ++rr) {
                const int gm = i0 + wm + mi * 16 + kg * 4 + rr;
                const int bb = gm >> 9;
                const int ss = gm & 511;
                wx[(size_t)(ss * B + bb) * H + gn] =
                    f32_to_bf16(acc[mi][ni][rr] + bwv[ni]);
            }
        }
    }
}

// ---------------------------------------------------------------------------
// K2: persistent recurrence, fence-free.
//  - 8 groups x 32 members (1 wg/CU). Member m: U rows [32m,32m+32) in LDS.
//  - h + flags flow through MALL via sc0 sc1 (write-through / bypass) ops.
//    NO __threadfence (no buffer_wbl2 / buffer_inv) anywhere in the loop.
//  - Ordering: h stores sc1 -> s_waitcnt vmcnt(0) -> barrier -> flag store.
//    Reader: poll flag -> sc1 bypass loads (MALL already has h).
// ---------------------------------------------------------------------------
__global__ __launch_bounds__(256) void k_rnn(
    const unsigned short* __restrict__ wx, const float* __restrict__ U,
    const float* __restrict__ Vw, const float* __restrict__ bv,
    float* __restrict__ hbuf, unsigned int* __restrict__ flags,
    float* __restrict__ out)
{
    __shared__ float U_lds[32 * 1024];   // 131072 B (swizzled)
    __shared__ float h_lds[8 * 1024];    //  32768 B (swizzled)

    const int t   = threadIdx.x;
    const int g   = blockIdx.x & 7;      // group: batches [8g, 8g+8)
    const int m   = blockIdx.x >> 3;     // member: j rows [32m, 32m+32)
    const int j0  = m * 32;
    const int bg0 = g * 8;

    // ---- stage U rows into LDS (swizzled: word k -> k ^ (((k>>6)&7)<<2)) ----
    {
        const int ksb = (t >> 4) & 7;
        const int dst = 4 * (t ^ ksb);
        for (int rr = 0; rr < 32; ++rr) {
            f32x4 v = *(const f32x4*)(U + (size_t)(j0 + rr) * H + t * 4);
            *(f32x4*)&U_lds[rr * 1024 + dst] = v;
        }
    }

    // compute-role mapping
    const int ks = t & 15;               // k-slice (64 k each)
    const int j2 = t >> 4;               // j-unit (2 rows each)
    const int k0 = ks * 64;
    const int sw = (ks & 7) << 2;

    // staging-role mapping: thread stages h[sb][smem*32 .. +32)
    const int sb   = t >> 5;
    const int smem = t & 31;
    const int sksb = (smem >> 1) & 7;

    // output element owned by this thread after allreduce
    const int jj = ks & 1, bi = ks >> 1;
    const int out_j = j0 + j2 * 2 + jj;
    const int out_b = bg0 + bi;

    unsigned int* fl = flags + g * 32;
    unsigned int* myflag = fl + m;

    float wxv = bf16_to_f32(wx[(size_t)(0 * B + out_b) * H + out_j]);

    __syncthreads();                     // U resident

    for (int ts = 0; ts < S; ++ts) {
        const float* hr = hbuf + (ts & 1) * (B * H);
        float*       hw = hbuf + ((ts + 1) & 1) * (B * H);

        // wait for the member whose chunk we stage (flag = steps published)
        while (__hip_atomic_load(&fl[smem], __ATOMIC_RELAXED,
                                 __HIP_MEMORY_SCOPE_AGENT) < (unsigned)ts) {}

        // prefetch next step's wx (h-independent, normal cached load)
        float wx_next = 0.f;
        if (ts + 1 < S)
            wx_next = bf16_to_f32(wx[(size_t)((ts + 1) * B + out_b) * H + out_j]);

        // bulk-stage 128B of h into LDS via MALL-bypass loads (swizzled)
        {
            const float* src = hr + (size_t)(bg0 + sb) * H + smem * 32;
            f32x4 vv[8];
            #pragma unroll
            for (int c = 0; c < 8; ++c) vv[c] = load_sc16(src + c * 4);
            asm volatile("s_waitcnt vmcnt(0)" ::: "memory");
            float* dstb = &h_lds[sb * 1024 + smem * 32];
            #pragma unroll
            for (int c = 0; c < 8; ++c)
                *(f32x4*)&dstb[4 * (c ^ sksb)] = vv[c];
        }
        __syncthreads();

        // compute: acc[jj 2][b 8] over k-slice [k0, k0+64)
        float acc[2][8] = {};
        const float* ub0 = &U_lds[(j2 * 2    ) * 1024 + k0];
        const float* ub1 = &U_lds[(j2 * 2 + 1) * 1024 + k0];
        const float* hb  = &h_lds[k0];
        #pragma unroll 4
        for (int kk = 0; kk < 64; kk += 4) {
            const int ko = kk ^ sw;
            const f32x4 u0 = *(const f32x4*)&ub0[ko];
            const f32x4 u1 = *(const f32x4*)&ub1[ko];
            #pragma unroll
            for (int bq = 0; bq < 8; ++bq) {
                const f32x4 h4 = *(const f32x4*)&hb[bq * 1024 + ko];
                acc[0][bq] += u0[0]*h4[0] + u0[1]*h4[1] + u0[2]*h4[2] + u0[3]*h4[3];
                acc[1][bq] += u1[0]*h4[0] + u1[1]*h4[1] + u1[2]*h4[2] + u1[3]*h4[3];
            }
        }

        // butterfly allreduce over the 16 k-slices (lanes t&15)
        #pragma unroll
        for (int q = 0; q < 16; ++q) {
            float v = acc[q & 1][q >> 1];
            v += __shfl_xor(v, 1);
            v += __shfl_xor(v, 2);
            v += __shfl_xor(v, 4);
            v += __shfl_xor(v, 8);
            acc[q & 1][q >> 1] = v;
        }
        float sum = 0.f;
        #pragma unroll
        for (int q = 0; q < 16; ++q)
            if (ks == q) sum = acc[q & 1][q >> 1];

        float p = wxv + sum;
        p = fminf(fmaxf(p, -15.f), 15.f);
        const float e  = __expf(2.0f * p);
        const float hv = 1.0f - 2.0f / (e + 1.0f);

        // publish h via write-through store; drain to MALL before barrier
        store_sc4(hw + (size_t)out_b * H + out_j, hv);
        asm volatile("s_waitcnt vmcnt(0)" ::: "memory");
        __syncthreads();                 // all waves' h stores at MALL
        if (t == 0)
            __hip_atomic_store(myflag, (unsigned)(ts + 1), __ATOMIC_RELAXED,
                               __HIP_MEMORY_SCOPE_AGENT);
        wxv = wx_next;
    }

    // ---- final projection: out[b][c] = h_final[b] . V[c] + bv[c] ----
    if (m == 0) {
        while (__hip_atomic_load(&fl[t & 31], __ATOMIC_RELAXED,
                                 __HIP_MEMORY_SCOPE_AGENT) < (unsigned)S) {}
        const float* hf = hbuf;          // S even -> final state in buf0
        const int o = t & 31, part = t >> 5;
        const int pb = o >> 2, c = o & 3;
        const float* hrow = hf + (size_t)(bg0 + pb) * H;
        const float* vrow = Vw + (size_t)c * H;
        float partial = 0.f;
        for (int jq = part * 128; jq < part * 128 + 128; jq += 4) {
            f32x4 hv4 = load_sc16(hrow + jq);
            asm volatile("s_waitcnt vmcnt(0)" ::: "memory");
            partial += hv4[0]*vrow[jq]   + hv4[1]*vrow[jq+1]
                     + hv4[2]*vrow[jq+2] + hv4[3]*vrow[jq+3];
        }
        __syncthreads();
        h_lds[part * 32 + o] = partial;
        __syncthreads();
        if (t < 32) {
            float sv = 0.f;
            #pragma unroll
            for (int pq = 0; pq < 8; ++pq) sv += h_lds[pq * 32 + t];
            out[(bg0 + (t >> 2)) * NCLS + (t & 3)] = sv + bv[t & 3];
        }
    }
}

// ---------------------------------------------------------------------------
extern "C" void kernel_launch(void* const* d_in, const int* in_sizes, int n_in,
                              void* d_out, int out_size, void* d_ws, size_t ws_size,
                              hipStream_t stream)
{
    const int*   x   = (const int*)d_in[0];
    const float* emb = (const float*)d_in[1];
    const float* W   = (const float*)d_in[2];
    const float* bw  = (const float*)d_in[3];
    const float* U   = (const float*)d_in[4];
    const float* V   = (const float*)d_in[5];
    const float* bv  = (const float*)d_in[6];
    float* out = (float*)d_out;

    unsigned short* wx = (unsigned short*)d_ws;
    const size_t WX_BYTES = (size_t)S * B * H * sizeof(unsigned short); // 64 MiB
    float* hbuf = (float*)((char*)d_ws + WX_BYTES);
    const size_t HB_BYTES = (size_t)2 * B * H * sizeof(float);          // 512 KiB
    unsigned int* flags = (unsigned int*)((char*)d_ws + WX_BYTES + HB_BYTES);

    // zero h0 double-buffer + flags every call (ws is not re-poisoned)
    hipMemsetAsync((char*)d_ws + WX_BYTES, 0, HB_BYTES + 1024, stream);

    hipLaunchKernelGGL(k_wx_gemm, dim3(256, 8), dim3(256), 0, stream,
                       x, emb, W, bw, wx);
    hipLaunchKernelGGL(k_rnn, dim3(256), dim3(256), 0, stream,
                       wx, U, V, bv, hbuf, flags, out);
}

// Round 4
// 1870.928 us; speedup vs baseline: 8.6402x; 2.6954x over previous
//
#include <hip/hip_runtime.h>
#include <stdint.h>

#define B 64
#define S 512
#define E 512
#define H 1024
#define NCLS 4

typedef __attribute__((ext_vector_type(8))) short short8;
typedef __attribute__((ext_vector_type(4))) float f32x4;

__device__ __forceinline__ unsigned short f32_to_bf16(float f) {
    unsigned int x = __float_as_uint(f);
    unsigned int r = (x + 0x7fffu + ((x >> 16) & 1u)) >> 16;   // RNE
    return (unsigned short)r;
}
__device__ __forceinline__ float bf16_to_f32(unsigned short u) {
    return __uint_as_float(((unsigned int)u) << 16);
}

// write-through store (L1+L2 bypass -> MALL coherence point)
__device__ __forceinline__ void store_sc4u(unsigned int* p, unsigned int v) {
    asm volatile("global_store_dword %0, %1, off sc0 sc1"
                 :: "v"(p), "v"(v) : "memory");
}

// ---------------------------------------------------------------------------
// K1: wx[s][b][j] = sum_k emb[x[b*S+s]][k] * W[j][k] + b_w[j], stored bf16.
// (unchanged from R1; verified correct)
// ---------------------------------------------------------------------------
#define K1_LDA 40

__global__ __launch_bounds__(256) void k_wx_gemm(
    const int* __restrict__ x, const float* __restrict__ emb,
    const float* __restrict__ W, const float* __restrict__ bw,
    unsigned short* __restrict__ wx)
{
    __shared__ unsigned short Asub[128 * K1_LDA];
    __shared__ unsigned short Bsub[128 * K1_LDA];

    const int t  = threadIdx.x;
    const int mt = blockIdx.x;
    const int nt = blockIdx.y;
    const int i0 = mt * 128;
    const int j0 = nt * 128;

    const int r  = t >> 1;
    const int kh = (t & 1) * 16;
    const int tok = x[i0 + r];
    const float* arow = emb + (size_t)tok * E;
    const float* brow = W + (size_t)(j0 + r) * E;

    const int lane = t & 63;
    const int w    = t >> 6;
    const int wm   = (w >> 1) * 64;
    const int wn   = (w & 1) * 64;
    const int fr   = lane & 15;
    const int kg   = lane >> 4;

    f32x4 acc[4][4] = {};

    for (int kt = 0; kt < E; kt += 32) {
        __syncthreads();
        {
            union { unsigned short us[8]; uint4 v; } p;
            const float* srcA = arow + kt + kh;
            #pragma unroll
            for (int i = 0; i < 8; ++i) p.us[i] = f32_to_bf16(srcA[i]);
            *(uint4*)&Asub[r * K1_LDA + kh] = p.v;
            #pragma unroll
            for (int i = 0; i < 8; ++i) p.us[i] = f32_to_bf16(srcA[8 + i]);
            *(uint4*)&Asub[r * K1_LDA + kh + 8] = p.v;
            const float* srcB = brow + kt + kh;
            #pragma unroll
            for (int i = 0; i < 8; ++i) p.us[i] = f32_to_bf16(srcB[i]);
            *(uint4*)&Bsub[r * K1_LDA + kh] = p.v;
            #pragma unroll
            for (int i = 0; i < 8; ++i) p.us[i] = f32_to_bf16(srcB[8 + i]);
            *(uint4*)&Bsub[r * K1_LDA + kh + 8] = p.v;
        }
        __syncthreads();

        short8 a[4], b[4];
        #pragma unroll
        for (int mi = 0; mi < 4; ++mi)
            a[mi] = *(const short8*)&Asub[(wm + mi * 16 + fr) * K1_LDA + kg * 8];
        #pragma unroll
        for (int ni = 0; ni < 4; ++ni)
            b[ni] = *(const short8*)&Bsub[(wn + ni * 16 + fr) * K1_LDA + kg * 8];
        #pragma unroll
        for (int mi = 0; mi < 4; ++mi)
            #pragma unroll
            for (int ni = 0; ni < 4; ++ni)
                acc[mi][ni] = __builtin_amdgcn_mfma_f32_16x16x32_bf16(
                                  a[mi], b[ni], acc[mi][ni], 0, 0, 0);
    }

    float bwv[4];
    #pragma unroll
    for (int ni = 0; ni < 4; ++ni) bwv[ni] = bw[j0 + wn + ni * 16 + fr];
    #pragma unroll
    for (int mi = 0; mi < 4; ++mi) {
        #pragma unroll
        for (int ni = 0; ni < 4; ++ni) {
            const int gn = j0 + wn + ni * 16 + fr;
            #pragma unroll
            for (int rr = 0; rr < 4; ++rr) {
                const int gm = i0 + wm + mi * 16 + kg * 4 + rr;
                const int bb = gm >> 9;
                const int ss = gm & 511;
                wx[(size_t)(ss * B + bb) * H + gn] =
                    f32_to_bf16(acc[mi][ni][rr] + bwv[ni]);
            }
        }
    }
}

// ---------------------------------------------------------------------------
// K2: persistent recurrence, MFMA split-bf16.
//  - 8 groups x 32 members (1 wg/CU). Member m owns j rows [32m, 32m+32).
//  - U resident in LDS as bf16 hi+lo planes (f32-equivalent precision),
//    XOR-swizzled (byte ^= (row&7)<<4) for conflict-free ds_read_b128.
//  - h travels packed (bf16hi<<16)|bf16lo per value, via MALL (sc0 sc1).
//  - Per step: poll 32 flags -> coalesced u64 bypass loads -> unpack into
//    H hi/lo planes -> 4 waves split K=1024, 48 MFMA each -> partial-C
//    reduce in LDS (aliased into Hhi) -> tanh -> packed publish + flag.
//  - LDS: 64K Uhi + 64K Ulo + 16K Hhi + 16K Hlo = 163840 B (exact max).
// ---------------------------------------------------------------------------
__global__ __launch_bounds__(256) void k_rnn(
    const unsigned short* __restrict__ wx, const float* __restrict__ U,
    const float* __restrict__ Vw, const float* __restrict__ bv,
    unsigned int* __restrict__ hbuf, unsigned int* __restrict__ flags,
    float* __restrict__ out)
{
    __shared__ __align__(16) unsigned short Uhi[32 * 1024];  // 64 KB
    __shared__ __align__(16) unsigned short Ulo[32 * 1024];  // 64 KB
    __shared__ __align__(16) unsigned short Hhi[8 * 1024];   // 16 KB
    __shared__ __align__(16) unsigned short Hlo[8 * 1024];   // 16 KB

    const int t   = threadIdx.x;
    const int g   = blockIdx.x & 7;      // group: batches [8g, 8g+8)
    const int m   = blockIdx.x >> 3;     // member: j rows [32m, 32m+32)
    const int j0  = m * 32;
    const int bg0 = g * 8;

    // ---- stage U -> hi/lo bf16 planes, swizzled ----
    for (int rr = 0; rr < 32; ++rr) {
        f32x4 v = *(const f32x4*)(U + (size_t)(j0 + rr) * H + t * 4);
        unsigned short h0 = f32_to_bf16(v[0]);
        unsigned short h1 = f32_to_bf16(v[1]);
        unsigned short h2 = f32_to_bf16(v[2]);
        unsigned short h3 = f32_to_bf16(v[3]);
        unsigned short l0 = f32_to_bf16(v[0] - bf16_to_f32(h0));
        unsigned short l1 = f32_to_bf16(v[1] - bf16_to_f32(h1));
        unsigned short l2 = f32_to_bf16(v[2] - bf16_to_f32(h2));
        unsigned short l3 = f32_to_bf16(v[3] - bf16_to_f32(h3));
        uint2 hwd, lwd;
        hwd.x = h0 | ((unsigned)h1 << 16); hwd.y = h2 | ((unsigned)h3 << 16);
        lwd.x = l0 | ((unsigned)l1 << 16); lwd.y = l2 | ((unsigned)l3 << 16);
        const int byteoff = (rr * 2048 + t * 8) ^ ((rr & 7) << 4);
        *(uint2*)((char*)Uhi + byteoff) = hwd;
        *(uint2*)((char*)Ulo + byteoff) = lwd;
    }

    // role constants
    const int lane  = t & 63;
    const int w     = t >> 6;            // wave id = K-chunk (256 k each)
    const int fr    = lane & 15;
    const int kg    = lane >> 4;         // 0..3
    const int kbase = w * 256;
    const int abrow = fr & 7;            // A (h) row: batches 8-15 duplicate 0-7
    const int ob    = t >> 5;            // output batch 0..7
    const int oj    = t & 31;            // output j local 0..31

    unsigned int* fl = flags + g * 32;
    float* redC = (float*)Hhi;           // 4 KB reduce buffer (time-aliased)
    unsigned int* Hh32 = (unsigned int*)Hhi;
    unsigned int* Hl32 = (unsigned int*)Hlo;

    float wxv = bf16_to_f32(wx[(size_t)(bg0 + ob) * H + j0 + oj]);

    __syncthreads();                     // U resident

    for (int ts = 0; ts < S; ++ts) {
        const unsigned int* hr = hbuf + (ts & 1) * (B * H);
        unsigned int*       hw = hbuf + ((ts + 1) & 1) * (B * H);

        // ---- wait for all 32 member flags (32 threads poll, rest barrier) --
        if (t < 32)
            while (__hip_atomic_load(&fl[t], __ATOMIC_RELAXED,
                                     __HIP_MEMORY_SCOPE_AGENT) < (unsigned)ts) {}
        __syncthreads();

        // prefetch next step's wx (h-independent, cached)
        float wx_next = 0.f;
        if (ts + 1 < S)
            wx_next = bf16_to_f32(wx[(size_t)((ts + 1) * B + bg0 + ob) * H + j0 + oj]);

        // ---- stage h: coalesced u64 bypass loads, then unpack to planes ----
        {
            const unsigned long long* src =
                (const unsigned long long*)(hr + (size_t)(bg0 + ob) * H);
            unsigned long long vv[16];
            #pragma unroll
            for (int i = 0; i < 16; ++i)
                vv[i] = __hip_atomic_load(src + oj + 32 * i, __ATOMIC_RELAXED,
                                          __HIP_MEMORY_SCOPE_AGENT);
            #pragma unroll
            for (int i = 0; i < 16; ++i) {
                const unsigned int v0 = (unsigned int)vv[i];
                const unsigned int v1 = (unsigned int)(vv[i] >> 32);
                const unsigned int hiw = (v0 >> 16) | (v1 & 0xffff0000u);
                const unsigned int low = (v0 & 0xffffu) | (v1 << 16);
                const int idx = (ob * 512 + oj + 32 * i) ^ (ob << 2);
                Hh32[idx] = hiw;
                Hl32[idx] = low;
            }
        }
        __syncthreads();

        // ---- MFMA: C[16b x 32j] over this wave's K-chunk, 3 split terms ----
        f32x4 acc0 = {}, acc1 = {};
        #pragma unroll
        for (int kk = 0; kk < 8; ++kk) {
            const int k  = kbase + kk * 32 + kg * 8;
            const int ab = (abrow * 2048 + k * 2) ^ (abrow << 4);
            const short8 ahi = *(const short8*)((const char*)Hhi + ab);
            const short8 alo = *(const short8*)((const char*)Hlo + ab);
            const int b0 = (fr * 2048 + k * 2) ^ ((fr & 7) << 4);
            const int b1 = ((16 + fr) * 2048 + k * 2) ^ ((fr & 7) << 4);
            const short8 bhi0 = *(const short8*)((const char*)Uhi + b0);
            const short8 blo0 = *(const short8*)((const char*)Ulo + b0);
            const short8 bhi1 = *(const short8*)((const char*)Uhi + b1);
            const short8 blo1 = *(const short8*)((const char*)Ulo + b1);
            acc0 = __builtin_amdgcn_mfma_f32_16x16x32_bf16(ahi, bhi0, acc0, 0, 0, 0);
            acc0 = __builtin_amdgcn_mfma_f32_16x16x32_bf16(ahi, blo0, acc0, 0, 0, 0);
            acc0 = __builtin_amdgcn_mfma_f32_16x16x32_bf16(alo, bhi0, acc0, 0, 0, 0);
            acc1 = __builtin_amdgcn_mfma_f32_16x16x32_bf16(ahi, bhi1, acc1, 0, 0, 0);
            acc1 = __builtin_amdgcn_mfma_f32_16x16x32_bf16(ahi, blo1, acc1, 0, 0, 0);
            acc1 = __builtin_amdgcn_mfma_f32_16x16x32_bf16(alo, bhi1, acc1, 0, 0, 0);
        }
        __syncthreads();                 // all H/U reads done before redC write

        // ---- cross-wave K-reduction via LDS ----
        if (kg < 2) {
            #pragma unroll
            for (int rr = 0; rr < 4; ++rr) {
                const int mb = kg * 4 + rr;          // batch row 0..7
                redC[w * 256 + mb * 32 + fr]      = acc0[rr];
                redC[w * 256 + mb * 32 + 16 + fr] = acc1[rr];
            }
        }
        __syncthreads();

        float sum = redC[       ob * 32 + oj] + redC[256 + ob * 32 + oj]
                  + redC[512 + ob * 32 + oj] + redC[768 + ob * 32 + oj];

        float p = wxv + sum;
        p = fminf(fmaxf(p, -15.f), 15.f);
        const float e  = __expf(2.0f * p);
        const float hv = 1.0f - 2.0f / (e + 1.0f);

        // pack hi|lo and publish via write-through store
        const unsigned short hib = f32_to_bf16(hv);
        const unsigned short lob = f32_to_bf16(hv - bf16_to_f32(hib));
        const unsigned int pk = ((unsigned int)hib << 16) | lob;
        store_sc4u(hw + (size_t)(bg0 + ob) * H + j0 + oj, pk);
        asm volatile("s_waitcnt vmcnt(0)" ::: "memory");
        __syncthreads();                 // all waves' h stores at MALL
        if (t == 0)
            __hip_atomic_store(&fl[m], (unsigned)(ts + 1), __ATOMIC_RELAXED,
                               __HIP_MEMORY_SCOPE_AGENT);
        wxv = wx_next;
    }

    // ---- final projection: out[b][c] = h_final[b] . V[c] + bv[c] ----
    if (m == 0) {
        if (t < 32)
            while (__hip_atomic_load(&fl[t], __ATOMIC_RELAXED,
                                     __HIP_MEMORY_SCOPE_AGENT) < (unsigned)S) {}
        __syncthreads();
        const unsigned int* hf = hbuf;   // S even -> final state in buf0
        const int o = t & 31, part = t >> 5;
        const int pb = o >> 2, c = o & 3;
        const unsigned long long* hrow =
            (const unsigned long long*)(hf + (size_t)(bg0 + pb) * H) + part * 64;
        const float* vrow = Vw + (size_t)c * H + part * 128;
        float partial = 0.f;
        for (int q = 0; q < 64; ++q) {
            unsigned long long vv = __hip_atomic_load(hrow + q, __ATOMIC_RELAXED,
                                                      __HIP_MEMORY_SCOPE_AGENT);
            const unsigned int v0 = (unsigned int)vv;
            const unsigned int v1 = (unsigned int)(vv >> 32);
            const float h0 = bf16_to_f32((unsigned short)(v0 >> 16))
                           + bf16_to_f32((unsigned short)(v0 & 0xffffu));
            const float h1 = bf16_to_f32((unsigned short)(v1 >> 16))
                           + bf16_to_f32((unsigned short)(v1 & 0xffffu));
            partial += h0 * vrow[2 * q] + h1 * vrow[2 * q + 1];
        }
        __syncthreads();
        redC[part * 32 + o] = partial;
        __syncthreads();
        if (t < 32) {
            float sv = 0.f;
            #pragma unroll
            for (int pq = 0; pq < 8; ++pq) sv += redC[pq * 32 + t];
            out[(bg0 + (t >> 2)) * NCLS + (t & 3)] = sv + bv[t & 3];
        }
    }
}

// ---------------------------------------------------------------------------
extern "C" void kernel_launch(void* const* d_in, const int* in_sizes, int n_in,
                              void* d_out, int out_size, void* d_ws, size_t ws_size,
                              hipStream_t stream)
{
    const int*   x   = (const int*)d_in[0];
    const float* emb = (const float*)d_in[1];
    const float* W   = (const float*)d_in[2];
    const float* bw  = (const float*)d_in[3];
    const float* U   = (const float*)d_in[4];
    const float* V   = (const float*)d_in[5];
    const float* bv  = (const float*)d_in[6];
    float* out = (float*)d_out;

    unsigned short* wx = (unsigned short*)d_ws;
    const size_t WX_BYTES = (size_t)S * B * H * sizeof(unsigned short); // 64 MiB
    unsigned int* hbuf = (unsigned int*)((char*)d_ws + WX_BYTES);
    const size_t HB_BYTES = (size_t)2 * B * H * sizeof(unsigned int);   // 512 KiB
    unsigned int* flags = (unsigned int*)((char*)d_ws + WX_BYTES + HB_BYTES);

    // zero h0 double-buffer + flags every call (ws is not re-poisoned)
    hipMemsetAsync((char*)d_ws + WX_BYTES, 0, HB_BYTES + 1024, stream);

    hipLaunchKernelGGL(k_wx_gemm, dim3(256, 8), dim3(256), 0, stream,
                       x, emb, W, bw, wx);
    hipLaunchKernelGGL(k_rnn, dim3(256), dim3(256), 0, stream,
                       wx, U, V, bv, hbuf, flags, out);
}